// Round 10
// baseline (196.500 us; speedup 1.0000x reference)
//
#include <hip/hip_runtime.h>
#include <hip/hip_bf16.h>

// Problem constants
#define B_SZ   64
#define L_SZ   52
#define DMODEL 4096
#define H_SZ   32
#define C_SZ   128   // NEW_C = DMODEL/H
#define DK     128   // D_K == D_V

// Output GEMM dims: (B*L) x DMODEL = 3328 x 4096, K = 4096
#define GM 3328
#define GN 4096
#define GK 4096

typedef __bf16 bf16x8 __attribute__((ext_vector_type(8)));
typedef float  f32x4  __attribute__((ext_vector_type(4)));

__device__ __forceinline__ void gload_lds16(const void* g, void* l) {
  __builtin_amdgcn_global_load_lds(
      (__attribute__((address_space(1))) void*)(void*)g,
      (__attribute__((address_space(3))) void*)l, 16, 0, 0);
}

__device__ __forceinline__ unsigned short bfbits(float x) {
  union { __hip_bfloat16 h; unsigned short u; } c;
  c.h = __float2bfloat16(x);
  return c.u;
}

// Swizzled region addressing (16B granules, involution g ^= row&7):
// bf16 region: 52 rows x 128 halfwords (13312 B), granule g in 0..15.
__device__ __forceinline__ int hwoff(int row, int g) {
  return row * 128 + ((g ^ (row & 7)) << 3);
}
// f32 region: 52 rows x 64 words (13312 B), granule g in 0..15 (4 words each).
__device__ __forceinline__ int wdoff(int row, int g) {
  return row * 64 + ((g ^ (row & 7)) << 2);
}

// ---------------------------------------------------------------------------
// Kernel 1b: Wq/Wk/Wv [h][c][k] fp32 -> [h][k][c] bf16   (batched 128x128 T)
// (stays separate: the fused attn kernel READS its outputs)
// ---------------------------------------------------------------------------
__global__ __launch_bounds__(256) void w3_transpose_kernel(
    const float* __restrict__ Wq, const float* __restrict__ Wk,
    const float* __restrict__ Wv, __hip_bfloat16* __restrict__ WqT,
    __hip_bfloat16* __restrict__ WkT, __hip_bfloat16* __restrict__ WvT) {
  __shared__ float tile[64][65];
  const int bz = blockIdx.z;
  const float* in = (bz < 32 ? Wq : (bz < 64 ? Wk : Wv)) + (size_t)(bz & 31) * 16384;
  __hip_bfloat16* out = (bz < 32 ? WqT : (bz < 64 ? WkT : WvT)) + (size_t)(bz & 31) * 16384;
  const int nt = blockIdx.x, mt = blockIdx.y;  // 0..1
  const int t = threadIdx.x;
  const int r  = t >> 4;
  const int c4 = (t & 15) << 2;
#pragma unroll
  for (int p = 0; p < 4; ++p) {
    const int rr = r + p * 16;
    const float4 v = *(const float4*)(in + (size_t)(mt * 64 + rr) * 128 + nt * 64 + c4);
    tile[rr][c4 + 0] = v.x; tile[rr][c4 + 1] = v.y;
    tile[rr][c4 + 2] = v.z; tile[rr][c4 + 3] = v.w;
  }
  __syncthreads();
#pragma unroll
  for (int p = 0; p < 4; ++p) {
    const int rr = r + p * 16;
    union { __hip_bfloat16 h[4]; ushort4 u; } o4;
#pragma unroll
    for (int e = 0; e < 4; ++e) o4.h[e] = __float2bfloat16(tile[c4 + e][rr]);
    *(ushort4*)(out + (size_t)(nt * 64 + rr) * 128 + mt * 64 + c4) = o4.u;
  }
}

// ---------------------------------------------------------------------------
// Kernel 2 (FUSED): blocks [0,2048) = per-(b,h) MFMA attention;
// blocks [2048,6144) = Wo transpose tiles. LDS 39936 B -> 4 blocks/CU.
// bf16 regions (swizzled, 13312 B each): r0: xs_q -> k_sh -> p_sh;
// r1: xs_k -> s_sh (f32, swizzled); r2: xs_v -> q_sh.
// q/k projections and PV use SWAPPED mfma operands: lane's 4 C-values are 4
// consecutive COLS -> b64 LDS stores (proj) and b64 global stores (Oc).
// Operand-swap validity: A and B fragments share the lane->(nonk,k) map
// (proven in-kernel: QK^T uses an A-style fragment as B since R2).
// ---------------------------------------------------------------------------
__device__ __forceinline__ void proj_swz(
    const __hip_bfloat16* __restrict__ xs, const __hip_bfloat16* __restrict__ WT,
    const float* __restrict__ bias, __hip_bfloat16* __restrict__ out,
    int n0, int r16, int kq) {
  f32x4 acc[2][4] = {};   // [col-16-block ct][row-16-block rt]
  bf16x8 wf[2][4];
#pragma unroll
  for (int ct = 0; ct < 2; ++ct)
#pragma unroll
    for (int kk = 0; kk < 4; ++kk)
      wf[ct][kk] = *(const bf16x8*)(WT + (n0 + ct * 16 + r16) * 128 + kk * 32 + kq * 8);
#pragma unroll
  for (int kk = 0; kk < 4; ++kk) {
    bf16x8 xf[4];
#pragma unroll
    for (int rt = 0; rt < 4; ++rt) {
      const int row = rt * 16 + r16;
      const int rowc = row < 52 ? row : 51;
      xf[rt] = *(const bf16x8*)(xs + hwoff(rowc, 4 * kk + kq));
    }
#pragma unroll
    for (int ct = 0; ct < 2; ++ct)
#pragma unroll
      for (int rt = 0; rt < 4; ++rt)
        acc[ct][rt] = __builtin_amdgcn_mfma_f32_16x16x32_bf16(wf[ct][kk], xf[rt], acc[ct][rt], 0, 0, 0);
  }
#pragma unroll
  for (int ct = 0; ct < 2; ++ct) {
    const int col0 = n0 + ct * 16 + kq * 4;
    const float4 b4 = *(const float4*)(bias + col0);
    const int g = (n0 >> 3) + ct * 2 + (kq >> 1);
#pragma unroll
    for (int rt = 0; rt < 4; ++rt) {
      const int row = rt * 16 + r16;
      if (row < 52) {
        ushort4 o;
        o.x = bfbits(acc[ct][rt][0] + b4.x);
        o.y = bfbits(acc[ct][rt][1] + b4.y);
        o.z = bfbits(acc[ct][rt][2] + b4.z);
        o.w = bfbits(acc[ct][rt][3] + b4.w);
        *(ushort4*)(out + hwoff(row, g) + (kq & 1) * 4) = o;
      }
    }
  }
}

__device__ __forceinline__ uint2 shfl64(uint2 v, int lane) {
  uint2 r;
  r.x = (unsigned)__shfl((int)v.x, lane);
  r.y = (unsigned)__shfl((int)v.y, lane);
  return r;
}

__global__ __launch_bounds__(256, 4) void attn_fused_kernel(
    const float* __restrict__ Qin, const float* __restrict__ Kin,
    const float* __restrict__ Vin,
    const __hip_bfloat16* __restrict__ WqT, const float* __restrict__ bq,
    const __hip_bfloat16* __restrict__ WkT, const float* __restrict__ bk,
    const __hip_bfloat16* __restrict__ WvT, const float* __restrict__ bv,
    __hip_bfloat16* __restrict__ Oc,
    const float* __restrict__ Wo, __hip_bfloat16* __restrict__ WoT) {
  __shared__ __align__(16) char lds[39936];
  const int gid = blockIdx.x;
  const int t = threadIdx.x;

  if (gid >= 2048) {
    // ---------------- Wo transpose tile (64x64) ----------------
    float* tile = (float*)lds;                     // [64][65] = 16640 B
    const int bid2 = gid - 2048;
    const int nt = bid2 & 63, mt = bid2 >> 6;
    const int r  = t >> 4;
    const int c4 = (t & 15) << 2;
#pragma unroll
    for (int p = 0; p < 4; ++p) {
      const int rr = r + p * 16;
      const float4 v = *(const float4*)(Wo + (size_t)(mt * 64 + rr) * 4096 + nt * 64 + c4);
      tile[rr * 65 + c4 + 0] = v.x; tile[rr * 65 + c4 + 1] = v.y;
      tile[rr * 65 + c4 + 2] = v.z; tile[rr * 65 + c4 + 3] = v.w;
    }
    __syncthreads();
#pragma unroll
    for (int p = 0; p < 4; ++p) {
      const int rr = r + p * 16;
      union { __hip_bfloat16 h[4]; ushort4 u; } o4;
#pragma unroll
      for (int e = 0; e < 4; ++e) o4.h[e] = __float2bfloat16(tile[(c4 + e) * 65 + rr]);
      *(ushort4*)(WoT + (size_t)(nt * 64 + rr) * 4096 + mt * 64 + c4) = o4.u;
    }
    return;
  }

  // ---------------- attention block ----------------
  __hip_bfloat16* r0 = (__hip_bfloat16*)(lds);           // xs_q -> k_sh -> p_sh
  __hip_bfloat16* r1 = (__hip_bfloat16*)(lds + 13312);   // xs_k -> s_sh
  __hip_bfloat16* r2 = (__hip_bfloat16*)(lds + 26624);   // xs_v -> q_sh
  float*          s_sh = (float*)(lds + 13312);          // 52 x 64 f32 (swizzled)
  __hip_bfloat16* p_sh = r0;                             // 52 x 64 bf16 (granules 0..7)

  const int h = gid & 31, bb = gid >> 5;
  const int lane = t & 63;
  const int w = t >> 6;
  const int r16 = lane & 15, kq = lane >> 4;
  const size_t xoff = (size_t)bb * (L_SZ * DMODEL) + (size_t)h * (L_SZ * C_SZ);
  const int n0 = w * 32;

  // ---- P0: stage X fp32 -> bf16 into swizzled regions ----
  {
    const float* xp[3] = {Qin + xoff, Kin + xoff, Vin + xoff};
    __hip_bfloat16* xd[3] = {r0, r1, r2};
#pragma unroll
    for (int tz = 0; tz < 3; ++tz) {
      const float* X = xp[tz];
      __hip_bfloat16* xs = xd[tz];
      for (int idx = t; idx < 52 * 32; idx += 256) {
        const int row = idx >> 5, c4 = (idx & 31) << 2;   // halfword col
        const float4 v = *(const float4*)(X + row * 128 + c4);
        union { __hip_bfloat16 h[4]; ushort4 u; } o4;
        o4.h[0] = __float2bfloat16(v.x); o4.h[1] = __float2bfloat16(v.y);
        o4.h[2] = __float2bfloat16(v.z); o4.h[3] = __float2bfloat16(v.w);
        *(ushort4*)(xs + hwoff(row, c4 >> 3) + (c4 & 4)) = o4.u;
      }
    }
  }
  __syncthreads();   // B1

  // ---- P1: vproj -> registers (unswapped; vb[mt][ct] rows kq*4..+3) ----
  uint2 vb[4][2];
  {
    f32x4 acc[4][2] = {};
    bf16x8 wf[2][4];
    const __hip_bfloat16* WT = WvT + (size_t)h * 16384;
#pragma unroll
    for (int ct = 0; ct < 2; ++ct)
#pragma unroll
      for (int kk = 0; kk < 4; ++kk)
        wf[ct][kk] = *(const bf16x8*)(WT + (n0 + ct * 16 + r16) * 128 + kk * 32 + kq * 8);
#pragma unroll
    for (int kk = 0; kk < 4; ++kk) {
      bf16x8 a[4];
#pragma unroll
      for (int mt = 0; mt < 4; ++mt) {
        const int row = mt * 16 + r16;
        const int rowc = row < 52 ? row : 51;
        a[mt] = *(const bf16x8*)(r2 + hwoff(rowc, 4 * kk + kq));
      }
#pragma unroll
      for (int mt = 0; mt < 4; ++mt)
#pragma unroll
        for (int ct = 0; ct < 2; ++ct)
          acc[mt][ct] = __builtin_amdgcn_mfma_f32_16x16x32_bf16(a[mt], wf[ct][kk], acc[mt][ct], 0, 0, 0);
    }
#pragma unroll
    for (int ct = 0; ct < 2; ++ct) {
      const float bvv = bv[h * 128 + n0 + ct * 16 + r16];
#pragma unroll
      for (int mt = 0; mt < 4; ++mt) {
        vb[mt][ct].x = (unsigned)bfbits(acc[mt][ct][0] + bvv) |
                       ((unsigned)bfbits(acc[mt][ct][1] + bvv) << 16);
        vb[mt][ct].y = (unsigned)bfbits(acc[mt][ct][2] + bvv) |
                       ((unsigned)bfbits(acc[mt][ct][3] + bvv) << 16);
      }
    }
  }
  __syncthreads();   // B2 (vproj done reading r2)

  // ---- P2: qproj r0 -> r2 (swapped, b64 stores) ----
  proj_swz(r0, WqT + (size_t)h * 16384, bq + h * 128, r2, n0, r16, kq);
  __syncthreads();   // B3

  // ---- P3: kproj r1 -> r0 (swapped) ----
  proj_swz(r1, WkT + (size_t)h * 16384, bk + h * 128, r0, n0, r16, kq);
  __syncthreads();   // B4

  // ---- P4: QK^T: q(r2) x k(r0) -> s_sh(r1), scaled ----
  {
    const int nq = w * 16;
    f32x4 sacc[4] = {};
#pragma unroll
    for (int kk = 0; kk < 4; ++kk) {
      const int krow = nq + r16;
      const int krc = krow < 52 ? krow : 51;
      const bf16x8 kf = *(const bf16x8*)(r0 + hwoff(krc, 4 * kk + kq));
#pragma unroll
      for (int mt = 0; mt < 4; ++mt) {
        const int qrow = mt * 16 + r16;
        const int qrc = qrow < 52 ? qrow : 51;
        const bf16x8 a = *(const bf16x8*)(r2 + hwoff(qrc, 4 * kk + kq));
        sacc[mt] = __builtin_amdgcn_mfma_f32_16x16x32_bf16(a, kf, sacc[mt], 0, 0, 0);
      }
    }
    const float scale = 0.08838834764831845f;  // 1/sqrt(128)
    const int c = nq + r16;
#pragma unroll
    for (int mt = 0; mt < 4; ++mt)
#pragma unroll
      for (int i = 0; i < 4; ++i) {
        const int row = mt * 16 + kq * 4 + i;
        if (row < 52) s_sh[wdoff(row, c >> 2) + (c & 3)] = sacc[mt][i] * scale;
      }
  }
  __syncthreads();   // B5

  // ---- P5: masked softmax s_sh(r1) -> p_sh(r0) ----
  {
    const int r = t >> 2, qd = t & 3;   // 4 lanes/row, 16 cols each
    if (r < 52) {
      float v[16];
      float mx = -3e38f;
#pragma unroll
      for (int j4 = 0; j4 < 4; ++j4) {
        const f32x4 s4 = *(const f32x4*)(s_sh + wdoff(r, qd * 4 + j4));
#pragma unroll
        for (int e = 0; e < 4; ++e) {
          const int col = qd * 16 + j4 * 4 + e;
          const float val = (col <= r) ? s4[e] : -3e38f;
          v[j4 * 4 + e] = val;
          mx = fmaxf(mx, val);
        }
      }
      mx = fmaxf(mx, __shfl_xor(mx, 1));
      mx = fmaxf(mx, __shfl_xor(mx, 2));
      float ex[16];
      float sum = 0.f;
#pragma unroll
      for (int j = 0; j < 16; ++j) {
        const int col = qd * 16 + j;
        const float e = (col <= r) ? __expf(v[j] - mx) : 0.f;
        ex[j] = e; sum += e;
      }
      sum += __shfl_xor(sum, 1);
      sum += __shfl_xor(sum, 2);
      const float inv = 1.0f / sum;
      union { __hip_bfloat16 h[8]; uint4 q; } p0, p1;
#pragma unroll
      for (int j = 0; j < 8; ++j) {
        p0.h[j] = __float2bfloat16(ex[j] * inv);
        p1.h[j] = __float2bfloat16(ex[8 + j] * inv);
      }
      *(uint4*)(p_sh + hwoff(r, qd * 2))     = p0.q;
      *(uint4*)(p_sh + hwoff(r, qd * 2 + 1)) = p1.q;
    }
  }
  __syncthreads();   // B6

  // ---- P6: PV (swapped): mfma(v_frag, p_frag) -> O^T layout, b64 Oc stores ----
  {
    const int half = (kq >> 1) & 1;
    const int src0 = ((kq & 1) << 5) + r16;
    const int src1 = src0 + 16;
    f32x4 oaccT[2][4] = {};   // [v-col block ct][q-row block rt]
#pragma unroll
    for (int kk = 0; kk < 2; ++kk) {
      bf16x8 bfr[2];
#pragma unroll
      for (int ct = 0; ct < 2; ++ct) {
        const uint2 a0 = shfl64(vb[2 * kk + 0][ct], src0);
        const uint2 a1 = shfl64(vb[2 * kk + 1][ct], src0);
        const uint2 b0 = shfl64(vb[2 * kk + 0][ct], src1);
        const uint2 b1 = shfl64(vb[2 * kk + 1][ct], src1);
        union { unsigned u[4]; bf16x8 v; } asm_;
        asm_.u[0] = half ? a1.x : a0.x;
        asm_.u[1] = half ? a1.y : a0.y;
        asm_.u[2] = half ? b1.x : b0.x;
        asm_.u[3] = half ? b1.y : b0.y;
        bfr[ct] = asm_.v;
      }
      bf16x8 pf[4];
#pragma unroll
      for (int rt = 0; rt < 4; ++rt) {
        const int prow = rt * 16 + r16;
        const int prc = prow < 52 ? prow : 51;
        pf[rt] = *(const bf16x8*)(p_sh + hwoff(prc, 4 * kk + kq));
      }
#pragma unroll
      for (int ct = 0; ct < 2; ++ct)
#pragma unroll
        for (int rt = 0; rt < 4; ++rt)
          oaccT[ct][rt] = __builtin_amdgcn_mfma_f32_16x16x32_bf16(bfr[ct], pf[rt], oaccT[ct][rt], 0, 0, 0);
    }
    const size_t obase = (size_t)bb * 52 * 4096 + (size_t)h * 128;
#pragma unroll
    for (int ct = 0; ct < 2; ++ct) {
      const int col0 = n0 + ct * 16 + kq * 4;
#pragma unroll
      for (int rt = 0; rt < 4; ++rt) {
        const int row = rt * 16 + r16;
        if (row < 52) {
          ushort4 o;
          o.x = bfbits(oaccT[ct][rt][0]);
          o.y = bfbits(oaccT[ct][rt][1]);
          o.z = bfbits(oaccT[ct][rt][2]);
          o.w = bfbits(oaccT[ct][rt][3]);
          *(ushort4*)(Oc + obase + (size_t)row * 4096 + col0) = o;
        }
      }
    }
  }
}

// ---------------------------------------------------------------------------
// Kernel 3: C = Oc @ WoT^T + bo — m201-style 4-phase/K-tile schedule,
// K-loop unrolled x2 (compile-time LDS buffer pointers). Unchanged from R9.
// ---------------------------------------------------------------------------
#define STAGE(GBASE, REGOFF, KT, KS, WB) do {                                  \
    const __hip_bfloat16* s_ = (GBASE) + (size_t)(KT) * 64 + (KS) * 32;        \
    char* d_ = (WB) + (REGOFF) + ((KS) ? 16384 : 0) + t * 16;                  \
    gload_lds16(s_, d_);                                                       \
    gload_lds16(s_ + (size_t)128 * GK, d_ + 8192);                             \
  } while (0)

#define MFMA16(MQ, BF)                                                         \
  __builtin_amdgcn_sched_barrier(0);                                           \
  __builtin_amdgcn_s_setprio(1);                                               \
  _Pragma("unroll")                                                            \
  for (int mf = 0; mf < 4; ++mf)                                               \
    _Pragma("unroll")                                                          \
    for (int nf = 0; nf < 4; ++nf)                                             \
      acc[(MQ) * 4 + mf][nf] = __builtin_amdgcn_mfma_f32_16x16x32_bf16(        \
          af[mf], BF[nf], acc[(MQ) * 4 + mf][nf], 0, 0, 0);                    \
  __builtin_amdgcn_s_setprio(0)

#define READ_AF(RB, KS, MQ)                                                    \
  _Pragma("unroll")                                                            \
  for (int mf = 0; mf < 4; ++mf)                                               \
    af[mf] = *(const bf16x8*)((RB) + (KS) * 16384 + (MQ) * 4096 + aB0 + mf * 1024)

#define READ_BF(RB, BF, KS)                                                    \
  _Pragma("unroll")                                                            \
  for (int nf = 0; nf < 4; ++nf)                                               \
    BF[nf] = *(const bf16x8*)((RB) + 32768 + (KS) * 16384 + bB0 + nf * 1024)

#define KTILE_BODY(KT, RB, OB) do {                                            \
    const int s1 = (KT) + 1 < 64 ? (KT) + 1 : 63;                              \
    const int s2 = (KT) + 2 < 64 ? (KT) + 2 : 63;                              \
    {                                                                          \
      bf16x8 af[4];                                                            \
      READ_AF(RB, 0, 0);                                                       \
      READ_BF(RB, bf0, 0);                                                     \
      STAGE(gA0, 0, s1, 1, OB);                                                \
      __builtin_amdgcn_s_barrier();                                            \
      asm volatile("s_waitcnt lgkmcnt(0)" ::: "memory");                       \
      MFMA16(0, bf0);                                                          \
      __builtin_amdgcn_s_barrier();                                            \
    }                                                                          \
    {                                                                          \
      bf16x8 af[4];                                                            \
      READ_AF(RB, 0, 1);                                                       \
      STAGE(gB0, 32768, s2, 0, RB);                                            \
      __builtin_amdgcn_s_barrier();                                            \
      asm volatile("s_waitcnt lgkmcnt(0)" ::: "memory");                       \
      MFMA16(1, bf0);                                                          \
      __builtin_amdgcn_s_barrier();                                            \
    }                                                                          \
    {                                                                          \
      bf16x8 af[4];                                                            \
      READ_AF(RB, 1, 0);                                                       \
      READ_BF(RB, bf1, 1);                                                     \
      STAGE(gA0, 0, s2, 0, RB);                                                \
      __builtin_amdgcn_s_barrier();                                            \
      asm volatile("s_waitcnt lgkmcnt(0)" ::: "memory");                       \
      MFMA16(0, bf1);                                                          \
      __builtin_amdgcn_s_barrier();                                            \
    }                                                                          \
    {                                                                          \
      bf16x8 af[4];                                                            \
      READ_AF(RB, 1, 1);                                                       \
      STAGE(gB0, 32768, s2, 1, RB);                                            \
      __builtin_amdgcn_s_barrier();                                            \
      asm volatile("s_waitcnt lgkmcnt(0)" ::: "memory");                       \
      MFMA16(1, bf1);                                                          \
      asm volatile("s_waitcnt vmcnt(6)" ::: "memory");                         \
      __builtin_amdgcn_s_barrier();                                            \
    }                                                                          \
  } while (0)

__global__ __launch_bounds__(512, 2) void out_gemm_kernel(
    const __hip_bfloat16* __restrict__ A, const __hip_bfloat16* __restrict__ Bt,
    const float* __restrict__ bias, float* __restrict__ C) {
  __shared__ __align__(16) char lds[131072];   // 2 bufs x 64 KB

  int bid = blockIdx.x;
  bid = (bid & 7) * 26 + (bid >> 3);     // XCD swizzle, 208 % 8 == 0 (bijective)
  const int tm = bid >> 4;               // 0..12
  const int tn = bid & 15;               // 0..15

  const int t = threadIdx.x;
  const int w = t >> 6, lane = t & 63;
  const int wm = w >> 2, wn = w & 3;     // 2M x 4N waves; wave tile 128x64
  const int r16 = lane & 15, kq = lane >> 4;

  const int srow = t >> 2;
  const int sgslot = (t & 3) ^ ((srow >> 1) & 3);
  const __hip_bfloat16* gA0 = A  + (size_t)(tm * 256 + srow) * GK + sgslot * 8;
  const __hip_bfloat16* gB0 = Bt + (size_t)(tn * 256 + srow) * GK + sgslot * 8;

  const int slotr = kq ^ ((r16 >> 1) & 3);
  const int aB0 = (wm * 128 + r16) * 64 + slotr * 16;
  const int bB0 = (wn * 64 + r16) * 64 + slotr * 16;

  f32x4 acc[8][4] = {};
  bf16x8 bf0[4], bf1[4];

  char* const buf0 = lds;
  char* const buf1 = lds + 65536;

  STAGE(gA0, 0,     0, 0, buf0);
  STAGE(gA0, 0,     0, 1, buf0);
  STAGE(gB0, 32768, 0, 0, buf0);
  STAGE(gB0, 32768, 0, 1, buf0);
  STAGE(gB0, 32768, 1, 0, buf1);
  STAGE(gA0, 0,     1, 0, buf1);
  STAGE(gB0, 32768, 1, 1, buf1);
  asm volatile("s_waitcnt vmcnt(6)" ::: "memory");   // T0's 8 loads landed
  __builtin_amdgcn_s_barrier();

#pragma unroll 1
  for (int kt2 = 0; kt2 < 32; ++kt2) {
    const int kt = kt2 * 2;
    KTILE_BODY(kt,     buf0, buf1);
    KTILE_BODY(kt + 1, buf1, buf0);
  }
  asm volatile("s_waitcnt vmcnt(0) lgkmcnt(0)" ::: "memory");

  const int row0 = tm * 256 + wm * 128 + kq * 4;
  const int col0 = tn * 256 + wn * 64 + r16;
#pragma unroll
  for (int nf = 0; nf < 4; ++nf) {
    const int col = col0 + nf * 16;
    const float bv = bias[col];
#pragma unroll
    for (int mf = 0; mf < 8; ++mf) {
      const int row = row0 + mf * 16;
#pragma unroll
      for (int i = 0; i < 4; ++i)
        C[(size_t)(row + i) * GN + col] = acc[mf][nf][i] + bv;
    }
  }
}

// ---------------------------------------------------------------------------
extern "C" void kernel_launch(void* const* d_in, const int* in_sizes, int n_in,
                              void* d_out, int out_size, void* d_ws, size_t ws_size,
                              hipStream_t stream) {
  const float* Q  = (const float*)d_in[0];
  const float* K  = (const float*)d_in[1];
  const float* V  = (const float*)d_in[2];
  const float* Wq = (const float*)d_in[3];
  const float* bq = (const float*)d_in[4];
  const float* Wk = (const float*)d_in[5];
  const float* bk = (const float*)d_in[6];
  const float* Wv = (const float*)d_in[7];
  const float* bv = (const float*)d_in[8];
  const float* Wo = (const float*)d_in[9];
  const float* bo = (const float*)d_in[10];
  float* out = (float*)d_out;

  char* wsb = (char*)d_ws;
  __hip_bfloat16* WoT = (__hip_bfloat16*)wsb;
  __hip_bfloat16* Oc  = (__hip_bfloat16*)(wsb + (size_t)GN * GK * 2);
  __hip_bfloat16* WqT = (__hip_bfloat16*)(wsb + (size_t)GN * GK * 2 + (size_t)GM * GN * 2);
  __hip_bfloat16* WkT = WqT + (size_t)H_SZ * C_SZ * DK;
  __hip_bfloat16* WvT = WkT + (size_t)H_SZ * C_SZ * DK;

  w3_transpose_kernel<<<dim3(2, 2, 96), 256, 0, stream>>>(Wq, Wk, Wv, WqT, WkT, WvT);
  attn_fused_kernel<<<dim3(2048 + 4096), 256, 0, stream>>>(
      Q, K, V, WqT, bq, WkT, bk, WvT, bv, Oc, Wo, WoT);
  out_gemm_kernel<<<dim3(13 * 16), 512, 0, stream>>>(Oc, WoT, bo, out);
}

// Round 11
// 185.577 us; speedup vs baseline: 1.0589x; 1.0589x over previous
//
#include <hip/hip_runtime.h>
#include <hip/hip_bf16.h>

// Problem constants
#define B_SZ   64
#define L_SZ   52
#define DMODEL 4096
#define H_SZ   32
#define C_SZ   128   // NEW_C = DMODEL/H
#define DK     128   // D_K == D_V

// Output GEMM dims: (B*L) x DMODEL = 3328 x 4096, K = 4096
#define GM 3328
#define GN 4096
#define GK 4096

typedef __bf16 bf16x8 __attribute__((ext_vector_type(8)));
typedef float  f32x4  __attribute__((ext_vector_type(4)));

__device__ __forceinline__ void gload_lds16(const void* g, void* l) {
  __builtin_amdgcn_global_load_lds(
      (__attribute__((address_space(1))) void*)(void*)g,
      (__attribute__((address_space(3))) void*)l, 16, 0, 0);
}

__device__ __forceinline__ unsigned short bfbits(float x) {
  union { __hip_bfloat16 h; unsigned short u; } c;
  c.h = __float2bfloat16(x);
  return c.u;
}

// ---------------------------------------------------------------------------
// Kernel 1b: Wq/Wk/Wv [h][c][k] fp32 -> [h][k][c] bf16   (batched 128x128 T)
// ---------------------------------------------------------------------------
__global__ __launch_bounds__(256) void w3_transpose_kernel(
    const float* __restrict__ Wq, const float* __restrict__ Wk,
    const float* __restrict__ Wv, __hip_bfloat16* __restrict__ WqT,
    __hip_bfloat16* __restrict__ WkT, __hip_bfloat16* __restrict__ WvT) {
  __shared__ float tile[64][65];
  const int bz = blockIdx.z;
  const float* in = (bz < 32 ? Wq : (bz < 64 ? Wk : Wv)) + (size_t)(bz & 31) * 16384;
  __hip_bfloat16* out = (bz < 32 ? WqT : (bz < 64 ? WkT : WvT)) + (size_t)(bz & 31) * 16384;
  const int nt = blockIdx.x, mt = blockIdx.y;  // 0..1
  const int t = threadIdx.x;
  const int r  = t >> 4;
  const int c4 = (t & 15) << 2;
#pragma unroll
  for (int p = 0; p < 4; ++p) {
    const int rr = r + p * 16;
    const float4 v = *(const float4*)(in + (size_t)(mt * 64 + rr) * 128 + nt * 64 + c4);
    tile[rr][c4 + 0] = v.x; tile[rr][c4 + 1] = v.y;
    tile[rr][c4 + 2] = v.z; tile[rr][c4 + 3] = v.w;
  }
  __syncthreads();
#pragma unroll
  for (int p = 0; p < 4; ++p) {
    const int rr = r + p * 16;
    union { __hip_bfloat16 h[4]; ushort4 u; } o4;
#pragma unroll
    for (int e = 0; e < 4; ++e) o4.h[e] = __float2bfloat16(tile[c4 + e][rr]);
    *(ushort4*)(out + (size_t)(nt * 64 + rr) * 128 + mt * 64 + c4) = o4.u;
  }
}

// ---------------------------------------------------------------------------
// Kernel 2 (FUSED): blocks [0,2048) = attention (R9 geometry: stride-136
// regions, 42432 B LDS, 3 blocks/CU); blocks [2048,6144) = Wo transpose.
// New vs R9: (1) P0 software-pipelined batch loads (~14 outstanding VMEM),
// (2) Wv fragments preloaded alongside P0 loads, (3) swapped-operand q/k
// projections (b64 LDS stores) and PV (ushort4 Oc stores).
// ---------------------------------------------------------------------------
__device__ __forceinline__ void proj_swap136(
    const __hip_bfloat16* __restrict__ xs, const __hip_bfloat16* __restrict__ WT,
    const float* __restrict__ bias, __hip_bfloat16* __restrict__ out,
    int n0, int r16, int kq) {
  f32x4 acc[2][4] = {};   // [col-16-block ct][row-16-block rt]
  bf16x8 wf[2][4];
#pragma unroll
  for (int ct = 0; ct < 2; ++ct)
#pragma unroll
    for (int kk = 0; kk < 4; ++kk)
      wf[ct][kk] = *(const bf16x8*)(WT + (n0 + ct * 16 + r16) * 128 + kk * 32 + kq * 8);
#pragma unroll
  for (int kk = 0; kk < 4; ++kk) {
    bf16x8 xf[4];
#pragma unroll
    for (int rt = 0; rt < 4; ++rt) {
      const int row = rt * 16 + r16;
      const int rowc = row < 52 ? row : 51;       // clamp: masked downstream
      xf[rt] = *(const bf16x8*)(xs + rowc * 136 + kk * 32 + kq * 8);
    }
#pragma unroll
    for (int ct = 0; ct < 2; ++ct)
#pragma unroll
      for (int rt = 0; rt < 4; ++rt)
        acc[ct][rt] = __builtin_amdgcn_mfma_f32_16x16x32_bf16(wf[ct][kk], xf[rt], acc[ct][rt], 0, 0, 0);
  }
  // lane holds out[row = rt*16+r16][col0..col0+3], col0 = n0+ct*16+kq*4
#pragma unroll
  for (int ct = 0; ct < 2; ++ct) {
    const int col0 = n0 + ct * 16 + kq * 4;
    const float4 b4 = *(const float4*)(bias + col0);
#pragma unroll
    for (int rt = 0; rt < 4; ++rt) {
      const int row = rt * 16 + r16;
      if (row < 52) {
        ushort4 o;
        o.x = bfbits(acc[ct][rt][0] + b4.x);
        o.y = bfbits(acc[ct][rt][1] + b4.y);
        o.z = bfbits(acc[ct][rt][2] + b4.z);
        o.w = bfbits(acc[ct][rt][3] + b4.w);
        *(ushort4*)(out + row * 136 + col0) = o;
      }
    }
  }
}

__device__ __forceinline__ uint2 shfl64(uint2 v, int lane) {
  uint2 r;
  r.x = (unsigned)__shfl((int)v.x, lane);
  r.y = (unsigned)__shfl((int)v.y, lane);
  return r;
}

__global__ __launch_bounds__(256, 3) void attn_fused_kernel(
    const float* __restrict__ Qin, const float* __restrict__ Kin,
    const float* __restrict__ Vin,
    const __hip_bfloat16* __restrict__ WqT, const float* __restrict__ bq,
    const __hip_bfloat16* __restrict__ WkT, const float* __restrict__ bk,
    const __hip_bfloat16* __restrict__ WvT, const float* __restrict__ bv,
    __hip_bfloat16* __restrict__ Oc,
    const float* __restrict__ Wo, __hip_bfloat16* __restrict__ WoT) {
  __shared__ __align__(16) char lds[42432];
  const int gid = blockIdx.x;
  const int t = threadIdx.x;

  if (gid >= 2048) {
    // ---------------- Wo transpose tile (64x64) ----------------
    float* tile = (float*)lds;                     // [64][65] = 16640 B
    const int bid2 = gid - 2048;
    const int nt = bid2 & 63, mt = bid2 >> 6;
    const int r  = t >> 4;
    const int c4 = (t & 15) << 2;
#pragma unroll
    for (int p = 0; p < 4; ++p) {
      const int rr = r + p * 16;
      const float4 v = *(const float4*)(Wo + (size_t)(mt * 64 + rr) * 4096 + nt * 64 + c4);
      tile[rr * 65 + c4 + 0] = v.x; tile[rr * 65 + c4 + 1] = v.y;
      tile[rr * 65 + c4 + 2] = v.z; tile[rr * 65 + c4 + 3] = v.w;
    }
    __syncthreads();
#pragma unroll
    for (int p = 0; p < 4; ++p) {
      const int rr = r + p * 16;
      union { __hip_bfloat16 h[4]; ushort4 u; } o4;
#pragma unroll
      for (int e = 0; e < 4; ++e) o4.h[e] = __float2bfloat16(tile[(c4 + e) * 65 + rr]);
      *(ushort4*)(WoT + (size_t)(nt * 64 + rr) * 4096 + mt * 64 + c4) = o4.u;
    }
    return;
  }

  // ---------------- attention block ----------------
  __hip_bfloat16* r0 = (__hip_bfloat16*)(lds);           // xs_q -> k_sh -> p_sh
  __hip_bfloat16* r1 = (__hip_bfloat16*)(lds + 14144);   // xs_k -> s_sh
  __hip_bfloat16* r2 = (__hip_bfloat16*)(lds + 28288);   // xs_v -> q_sh
  float*          s_sh = (float*)(lds + 14144);          // 52 x 68 f32
  __hip_bfloat16* p_sh = r0;                             // 52 x 72 bf16

  const int h = gid & 31, bb = gid >> 5;
  const int lane = t & 63;
  const int w = t >> 6;
  const int r16 = lane & 15, kq = lane >> 4;
  const size_t xoff = (size_t)bb * (L_SZ * DMODEL) + (size_t)h * (L_SZ * C_SZ);
  const int n0 = w * 32;

  // ---- P0: batched staging, software-pipelined (MLP ~14 outstanding) ----
#define LOADR(G, XP)                                                           \
  _Pragma("unroll")                                                            \
  for (int j = 0; j < 7; ++j) {                                                \
    const int idx = t + j * 256;                                               \
    if (idx < 1664)                                                            \
      G[j] = *(const float4*)((XP) + (idx >> 5) * 128 + ((idx & 31) << 2));    \
  }
#define STORER(G, XD)                                                          \
  _Pragma("unroll")                                                            \
  for (int j = 0; j < 7; ++j) {                                                \
    const int idx = t + j * 256;                                               \
    if (idx < 1664) {                                                          \
      ushort4 o;                                                               \
      o.x = bfbits(G[j].x); o.y = bfbits(G[j].y);                              \
      o.z = bfbits(G[j].z); o.w = bfbits(G[j].w);                              \
      *(ushort4*)((XD) + (idx >> 5) * 136 + ((idx & 31) << 2)) = o;            \
    }                                                                          \
  }
  bf16x8 wfv[2][4];
  {
    float4 ga[7], gb[7];
    LOADR(ga, Qin + xoff)
    LOADR(gb, Kin + xoff)
    // Wv fragment preload overlaps the X loads (used first after B1)
    const __hip_bfloat16* WTv = WvT + (size_t)h * 16384;
#pragma unroll
    for (int ct = 0; ct < 2; ++ct)
#pragma unroll
      for (int kk = 0; kk < 4; ++kk)
        wfv[ct][kk] = *(const bf16x8*)(WTv + (n0 + ct * 16 + r16) * 128 + kk * 32 + kq * 8);
    STORER(ga, r0)
    LOADR(ga, Vin + xoff)
    STORER(gb, r1)
    STORER(ga, r2)
  }
  __syncthreads();   // B1

  // ---- P1: vproj -> registers (unswapped; vb[mt][ct] rows kq*4..+3) ----
  uint2 vb[4][2];
  {
    f32x4 acc[4][2] = {};
#pragma unroll
    for (int kk = 0; kk < 4; ++kk) {
      bf16x8 a[4];
#pragma unroll
      for (int mt = 0; mt < 4; ++mt) {
        const int row = mt * 16 + r16;
        const int rowc = row < 52 ? row : 51;
        a[mt] = *(const bf16x8*)(r2 + rowc * 136 + kk * 32 + kq * 8);
      }
#pragma unroll
      for (int mt = 0; mt < 4; ++mt)
#pragma unroll
        for (int ct = 0; ct < 2; ++ct)
          acc[mt][ct] = __builtin_amdgcn_mfma_f32_16x16x32_bf16(a[mt], wfv[ct][kk], acc[mt][ct], 0, 0, 0);
    }
#pragma unroll
    for (int ct = 0; ct < 2; ++ct) {
      const float bvv = bv[h * 128 + n0 + ct * 16 + r16];
#pragma unroll
      for (int mt = 0; mt < 4; ++mt) {
        vb[mt][ct].x = (unsigned)bfbits(acc[mt][ct][0] + bvv) |
                       ((unsigned)bfbits(acc[mt][ct][1] + bvv) << 16);
        vb[mt][ct].y = (unsigned)bfbits(acc[mt][ct][2] + bvv) |
                       ((unsigned)bfbits(acc[mt][ct][3] + bvv) << 16);
      }
    }
  }
  __syncthreads();   // B2 (vproj done reading r2)

  // ---- P2: qproj r0 -> r2 (swapped, b64 stores) ----
  proj_swap136(r0, WqT + (size_t)h * 16384, bq + h * 128, r2, n0, r16, kq);
  __syncthreads();   // B3

  // ---- P3: kproj r1 -> r0 (swapped) ----
  proj_swap136(r1, WkT + (size_t)h * 16384, bk + h * 128, r0, n0, r16, kq);
  __syncthreads();   // B4

  // ---- P4: QK^T: q(r2) x k(r0) -> s_sh(r1), scaled ----
  {
    const int nq = w * 16;
    f32x4 sacc[4] = {};
#pragma unroll
    for (int kk = 0; kk < 4; ++kk) {
      const int krow = nq + r16;
      const int krc = krow < 52 ? krow : 51;
      const bf16x8 kf = *(const bf16x8*)(r0 + krc * 136 + kk * 32 + kq * 8);
#pragma unroll
      for (int mt = 0; mt < 4; ++mt) {
        const int qrow = mt * 16 + r16;
        const int qrc = qrow < 52 ? qrow : 51;
        const bf16x8 a = *(const bf16x8*)(r2 + qrc * 136 + kk * 32 + kq * 8);
        sacc[mt] = __builtin_amdgcn_mfma_f32_16x16x32_bf16(a, kf, sacc[mt], 0, 0, 0);
      }
    }
    const float scale = 0.08838834764831845f;  // 1/sqrt(128)
#pragma unroll
    for (int mt = 0; mt < 4; ++mt)
#pragma unroll
      for (int i = 0; i < 4; ++i) {
        const int row = mt * 16 + kq * 4 + i;
        if (row < 52) s_sh[row * 68 + nq + r16] = sacc[mt][i] * scale;
      }
  }
  __syncthreads();   // B5

  // ---- P5: masked softmax s_sh(r1) -> p_sh(r0, stride 72) ----
  {
    const int r = t >> 2, qd = t & 3;   // 4 lanes/row, 16 cols each
    if (r < 52) {
      float v[16];
      float mx = -3e38f;
#pragma unroll
      for (int j4 = 0; j4 < 4; ++j4) {
        const f32x4 s4 = *(const f32x4*)(s_sh + r * 68 + qd * 16 + j4 * 4);
#pragma unroll
        for (int e = 0; e < 4; ++e) {
          const int col = qd * 16 + j4 * 4 + e;
          const float val = (col <= r) ? s4[e] : -3e38f;
          v[j4 * 4 + e] = val;
          mx = fmaxf(mx, val);
        }
      }
      mx = fmaxf(mx, __shfl_xor(mx, 1));
      mx = fmaxf(mx, __shfl_xor(mx, 2));
      float ex[16];
      float sum = 0.f;
#pragma unroll
      for (int j = 0; j < 16; ++j) {
        const int col = qd * 16 + j;
        const float e = (col <= r) ? __expf(v[j] - mx) : 0.f;
        ex[j] = e; sum += e;
      }
      sum += __shfl_xor(sum, 1);
      sum += __shfl_xor(sum, 2);
      const float inv = 1.0f / sum;
      union { __hip_bfloat16 h[8]; uint4 q; } p0, p1;
#pragma unroll
      for (int j = 0; j < 8; ++j) {
        p0.h[j] = __float2bfloat16(ex[j] * inv);
        p1.h[j] = __float2bfloat16(ex[8 + j] * inv);
      }
      *(uint4*)(p_sh + r * 72 + qd * 16)     = p0.q;
      *(uint4*)(p_sh + r * 72 + qd * 16 + 8) = p1.q;
    }
  }
  __syncthreads();   // B6

  // ---- P6: PV (swapped): mfma(v_frag, p_frag); ushort4 Oc stores ----
  {
    const int half = (kq >> 1) & 1;
    const int src0 = ((kq & 1) << 5) + r16;
    const int src1 = src0 + 16;
    f32x4 oaccT[2][4] = {};   // [v-col block ct][q-row block rt]
#pragma unroll
    for (int kk = 0; kk < 2; ++kk) {
      bf16x8 bfr[2];
#pragma unroll
      for (int ct = 0; ct < 2; ++ct) {
        const uint2 a0 = shfl64(vb[2 * kk + 0][ct], src0);
        const uint2 a1 = shfl64(vb[2 * kk + 1][ct], src0);
        const uint2 b0 = shfl64(vb[2 * kk + 0][ct], src1);
        const uint2 b1 = shfl64(vb[2 * kk + 1][ct], src1);
        union { unsigned u[4]; bf16x8 v; } asm_;
        asm_.u[0] = half ? a1.x : a0.x;
        asm_.u[1] = half ? a1.y : a0.y;
        asm_.u[2] = half ? b1.x : b0.x;
        asm_.u[3] = half ? b1.y : b0.y;
        bfr[ct] = asm_.v;
      }
      bf16x8 pf[4];
#pragma unroll
      for (int rt = 0; rt < 4; ++rt) {
        const int prow = rt * 16 + r16;
        const int prc = prow < 52 ? prow : 51;
        pf[rt] = *(const bf16x8*)(p_sh + prc * 72 + kk * 32 + kq * 8);
      }
#pragma unroll
      for (int ct = 0; ct < 2; ++ct)
#pragma unroll
        for (int rt = 0; rt < 4; ++rt)
          oaccT[ct][rt] = __builtin_amdgcn_mfma_f32_16x16x32_bf16(bfr[ct], pf[rt], oaccT[ct][rt], 0, 0, 0);
    }
    const size_t obase = (size_t)bb * 52 * 4096 + (size_t)h * 128;
#pragma unroll
    for (int ct = 0; ct < 2; ++ct) {
      const int col0 = n0 + ct * 16 + kq * 4;
#pragma unroll
      for (int rt = 0; rt < 4; ++rt) {
        const int row = rt * 16 + r16;
        if (row < 52) {
          ushort4 o;
          o.x = bfbits(oaccT[ct][rt][0]);
          o.y = bfbits(oaccT[ct][rt][1]);
          o.z = bfbits(oaccT[ct][rt][2]);
          o.w = bfbits(oaccT[ct][rt][3]);
          *(ushort4*)(Oc + obase + (size_t)row * 4096 + col0) = o;
        }
      }
    }
  }
}

// ---------------------------------------------------------------------------
// Kernel 3: C = Oc @ WoT^T + bo — m201-style 4-phase/K-tile schedule,
// x2-unrolled K-loop. NEW: swapped MFMA operands -> lane holds 4 consecutive
// COLUMNS -> epilogue is 32 coalesced float4 stores (was 128 dwords).
// ---------------------------------------------------------------------------
#define STAGE(GBASE, REGOFF, KT, KS, WB) do {                                  \
    const __hip_bfloat16* s_ = (GBASE) + (size_t)(KT) * 64 + (KS) * 32;        \
    char* d_ = (WB) + (REGOFF) + ((KS) ? 16384 : 0) + t * 16;                  \
    gload_lds16(s_, d_);                                                       \
    gload_lds16(s_ + (size_t)128 * GK, d_ + 8192);                             \
  } while (0)

#define MFMA16(MQ, BF)                                                         \
  __builtin_amdgcn_sched_barrier(0);                                           \
  __builtin_amdgcn_s_setprio(1);                                               \
  _Pragma("unroll")                                                            \
  for (int mf = 0; mf < 4; ++mf)                                               \
    _Pragma("unroll")                                                          \
    for (int nf = 0; nf < 4; ++nf)                                             \
      acc[(MQ) * 4 + mf][nf] = __builtin_amdgcn_mfma_f32_16x16x32_bf16(        \
          BF[nf], af[mf], acc[(MQ) * 4 + mf][nf], 0, 0, 0);                    \
  __builtin_amdgcn_s_setprio(0)

#define READ_AF(RB, KS, MQ)                                                    \
  _Pragma("unroll")                                                            \
  for (int mf = 0; mf < 4; ++mf)                                               \
    af[mf] = *(const bf16x8*)((RB) + (KS) * 16384 + (MQ) * 4096 + aB0 + mf * 1024)

#define READ_BF(RB, BF, KS)                                                    \
  _Pragma("unroll")                                                            \
  for (int nf = 0; nf < 4; ++nf)                                               \
    BF[nf] = *(const bf16x8*)((RB) + 32768 + (KS) * 16384 + bB0 + nf * 1024)

#define KTILE_BODY(KT, RB, OB) do {                                            \
    const int s1 = (KT) + 1 < 64 ? (KT) + 1 : 63;                              \
    const int s2 = (KT) + 2 < 64 ? (KT) + 2 : 63;                              \
    {                                                                          \
      bf16x8 af[4];                                                            \
      READ_AF(RB, 0, 0);                                                       \
      READ_BF(RB, bf0, 0);                                                     \
      STAGE(gA0, 0, s1, 1, OB);                                                \
      __builtin_amdgcn_s_barrier();                                            \
      asm volatile("s_waitcnt lgkmcnt(0)" ::: "memory");                       \
      MFMA16(0, bf0);                                                          \
      __builtin_amdgcn_s_barrier();                                            \
    }                                                                          \
    {                                                                          \
      bf16x8 af[4];                                                            \
      READ_AF(RB, 0, 1);                                                       \
      STAGE(gB0, 32768, s2, 0, RB);                                            \
      __builtin_amdgcn_s_barrier();                                            \
      asm volatile("s_waitcnt lgkmcnt(0)" ::: "memory");                       \
      MFMA16(1, bf0);                                                          \
      __builtin_amdgcn_s_barrier();                                            \
    }                                                                          \
    {                                                                          \
      bf16x8 af[4];                                                            \
      READ_AF(RB, 1, 0);                                                       \
      READ_BF(RB, bf1, 1);                                                     \
      STAGE(gA0, 0, s2, 0, RB);                                                \
      __builtin_amdgcn_s_barrier();                                            \
      asm volatile("s_waitcnt lgkmcnt(0)" ::: "memory");                       \
      MFMA16(0, bf1);                                                          \
      __builtin_amdgcn_s_barrier();                                            \
    }                                                                          \
    {                                                                          \
      bf16x8 af[4];                                                            \
      READ_AF(RB, 1, 1);                                                       \
      STAGE(gB0, 32768, s2, 1, RB);                                            \
      __builtin_amdgcn_s_barrier();                                            \
      asm volatile("s_waitcnt lgkmcnt(0)" ::: "memory");                       \
      MFMA16(1, bf1);                                                          \
      asm volatile("s_waitcnt vmcnt(6)" ::: "memory");                         \
      __builtin_amdgcn_s_barrier();                                            \
    }                                                                          \
  } while (0)

__global__ __launch_bounds__(512, 2) void out_gemm_kernel(
    const __hip_bfloat16* __restrict__ A, const __hip_bfloat16* __restrict__ Bt,
    const float* __restrict__ bias, float* __restrict__ C) {
  __shared__ __align__(16) char lds[131072];   // 2 bufs x 64 KB

  int bid = blockIdx.x;
  bid = (bid & 7) * 26 + (bid >> 3);     // XCD swizzle, 208 % 8 == 0 (bijective)
  const int tm = bid >> 4;               // 0..12
  const int tn = bid & 15;               // 0..15

  const int t = threadIdx.x;
  const int w = t >> 6, lane = t & 63;
  const int wm = w >> 2, wn = w & 3;     // 2M x 4N waves; wave tile 128x64
  const int r16 = lane & 15, kq = lane >> 4;

  const int srow = t >> 2;
  const int sgslot = (t & 3) ^ ((srow >> 1) & 3);
  const __hip_bfloat16* gA0 = A  + (size_t)(tm * 256 + srow) * GK + sgslot * 8;
  const __hip_bfloat16* gB0 = Bt + (size_t)(tn * 256 + srow) * GK + sgslot * 8;

  const int slotr = kq ^ ((r16 >> 1) & 3);
  const int aB0 = (wm * 128 + r16) * 64 + slotr * 16;
  const int bB0 = (wn * 64 + r16) * 64 + slotr * 16;

  f32x4 acc[8][4] = {};
  bf16x8 bf0[4], bf1[4];

  char* const buf0 = lds;
  char* const buf1 = lds + 65536;

  STAGE(gA0, 0,     0, 0, buf0);
  STAGE(gA0, 0,     0, 1, buf0);
  STAGE(gB0, 32768, 0, 0, buf0);
  STAGE(gB0, 32768, 0, 1, buf0);
  STAGE(gB0, 32768, 1, 0, buf1);
  STAGE(gA0, 0,     1, 0, buf1);
  STAGE(gB0, 32768, 1, 1, buf1);
  asm volatile("s_waitcnt vmcnt(6)" ::: "memory");   // T0's 8 loads landed
  __builtin_amdgcn_s_barrier();

#pragma unroll 1
  for (int kt2 = 0; kt2 < 32; ++kt2) {
    const int kt = kt2 * 2;
    KTILE_BODY(kt,     buf0, buf1);
    KTILE_BODY(kt + 1, buf1, buf0);
  }
  asm volatile("s_waitcnt vmcnt(0) lgkmcnt(0)" ::: "memory");

  // epilogue (swapped): lane holds C[row0+mf*16][col0 + nf*16 .. +3]
  const int row0 = tm * 256 + wm * 128 + r16;
  const int col0 = tn * 256 + wn * 64 + kq * 4;
  float4 b4[4];
#pragma unroll
  for (int nf = 0; nf < 4; ++nf)
    b4[nf] = *(const float4*)(bias + col0 + nf * 16);
#pragma unroll
  for (int mf = 0; mf < 8; ++mf) {
    const int row = row0 + mf * 16;
#pragma unroll
    for (int nf = 0; nf < 4; ++nf) {
      float4 st;
      st.x = acc[mf][nf][0] + b4[nf].x;
      st.y = acc[mf][nf][1] + b4[nf].y;
      st.z = acc[mf][nf][2] + b4[nf].z;
      st.w = acc[mf][nf][3] + b4[nf].w;
      *(float4*)(C + (size_t)row * GN + col0 + nf * 16) = st;
    }
  }
}

// ---------------------------------------------------------------------------
extern "C" void kernel_launch(void* const* d_in, const int* in_sizes, int n_in,
                              void* d_out, int out_size, void* d_ws, size_t ws_size,
                              hipStream_t stream) {
  const float* Q  = (const float*)d_in[0];
  const float* K  = (const float*)d_in[1];
  const float* V  = (const float*)d_in[2];
  const float* Wq = (const float*)d_in[3];
  const float* bq = (const float*)d_in[4];
  const float* Wk = (const float*)d_in[5];
  const float* bk = (const float*)d_in[6];
  const float* Wv = (const float*)d_in[7];
  const float* bv = (const float*)d_in[8];
  const float* Wo = (const float*)d_in[9];
  const float* bo = (const float*)d_in[10];
  float* out = (float*)d_out;

  char* wsb = (char*)d_ws;
  __hip_bfloat16* WoT = (__hip_bfloat16*)wsb;
  __hip_bfloat16* Oc  = (__hip_bfloat16*)(wsb + (size_t)GN * GK * 2);
  __hip_bfloat16* WqT = (__hip_bfloat16*)(wsb + (size_t)GN * GK * 2 + (size_t)GM * GN * 2);
  __hip_bfloat16* WkT = WqT + (size_t)H_SZ * C_SZ * DK;
  __hip_bfloat16* WvT = WkT + (size_t)H_SZ * C_SZ * DK;

  w3_transpose_kernel<<<dim3(2, 2, 96), 256, 0, stream>>>(Wq, Wk, Wv, WqT, WkT, WvT);
  attn_fused_kernel<<<dim3(2048 + 4096), 256, 0, stream>>>(
      Q, K, V, WqT, bq, WkT, bk, WvT, bv, Oc, Wo, WoT);
  out_gemm_kernel<<<dim3(13 * 16), 512, 0, stream>>>(Oc, WoT, bo, out);
}

// Round 12
// 184.644 us; speedup vs baseline: 1.0642x; 1.0051x over previous
//
#include <hip/hip_runtime.h>
#include <hip/hip_bf16.h>

// Problem constants
#define B_SZ   64
#define L_SZ   52
#define DMODEL 4096
#define H_SZ   32
#define C_SZ   128   // NEW_C = DMODEL/H
#define DK     128   // D_K == D_V

// Output GEMM dims: (B*L) x DMODEL = 3328 x 4096, K = 4096
#define GM 3328
#define GN 4096
#define GK 4096

typedef __bf16 bf16x8 __attribute__((ext_vector_type(8)));
typedef float  f32x4  __attribute__((ext_vector_type(4)));

__device__ __forceinline__ void gload_lds16(const void* g, void* l) {
  __builtin_amdgcn_global_load_lds(
      (__attribute__((address_space(1))) void*)(void*)g,
      (__attribute__((address_space(3))) void*)l, 16, 0, 0);
}

__device__ __forceinline__ unsigned short bfbits(float x) {
  union { __hip_bfloat16 h; unsigned short u; } c;
  c.h = __float2bfloat16(x);
  return c.u;
}

// ---------------------------------------------------------------------------
// Kernel 1b: Wq/Wk/Wv [h][c][k] fp32 -> [h][k][c] bf16   (batched 128x128 T)
// ---------------------------------------------------------------------------
__global__ __launch_bounds__(256) void w3_transpose_kernel(
    const float* __restrict__ Wq, const float* __restrict__ Wk,
    const float* __restrict__ Wv, __hip_bfloat16* __restrict__ WqT,
    __hip_bfloat16* __restrict__ WkT, __hip_bfloat16* __restrict__ WvT) {
  __shared__ float tile[64][65];
  const int bz = blockIdx.z;
  const float* in = (bz < 32 ? Wq : (bz < 64 ? Wk : Wv)) + (size_t)(bz & 31) * 16384;
  __hip_bfloat16* out = (bz < 32 ? WqT : (bz < 64 ? WkT : WvT)) + (size_t)(bz & 31) * 16384;
  const int nt = blockIdx.x, mt = blockIdx.y;  // 0..1
  const int t = threadIdx.x;
  const int r  = t >> 4;
  const int c4 = (t & 15) << 2;
#pragma unroll
  for (int p = 0; p < 4; ++p) {
    const int rr = r + p * 16;
    const float4 v = *(const float4*)(in + (size_t)(mt * 64 + rr) * 128 + nt * 64 + c4);
    tile[rr][c4 + 0] = v.x; tile[rr][c4 + 1] = v.y;
    tile[rr][c4 + 2] = v.z; tile[rr][c4 + 3] = v.w;
  }
  __syncthreads();
#pragma unroll
  for (int p = 0; p < 4; ++p) {
    const int rr = r + p * 16;
    union { __hip_bfloat16 h[4]; ushort4 u; } o4;
#pragma unroll
    for (int e = 0; e < 4; ++e) o4.h[e] = __float2bfloat16(tile[c4 + e][rr]);
    *(ushort4*)(out + (size_t)(nt * 64 + rr) * 128 + mt * 64 + c4) = o4.u;
  }
}

// ---------------------------------------------------------------------------
// Kernel 2 (FUSED): blocks [0,2048) = attention (stride-136 regions,
// 42432 B LDS, 3 blocks/CU); blocks [2048,6144) = Wo transpose. (as R11)
// ---------------------------------------------------------------------------
__device__ __forceinline__ void proj_swap136(
    const __hip_bfloat16* __restrict__ xs, const __hip_bfloat16* __restrict__ WT,
    const float* __restrict__ bias, __hip_bfloat16* __restrict__ out,
    int n0, int r16, int kq) {
  f32x4 acc[2][4] = {};   // [col-16-block ct][row-16-block rt]
  bf16x8 wf[2][4];
#pragma unroll
  for (int ct = 0; ct < 2; ++ct)
#pragma unroll
    for (int kk = 0; kk < 4; ++kk)
      wf[ct][kk] = *(const bf16x8*)(WT + (n0 + ct * 16 + r16) * 128 + kk * 32 + kq * 8);
#pragma unroll
  for (int kk = 0; kk < 4; ++kk) {
    bf16x8 xf[4];
#pragma unroll
    for (int rt = 0; rt < 4; ++rt) {
      const int row = rt * 16 + r16;
      const int rowc = row < 52 ? row : 51;       // clamp: masked downstream
      xf[rt] = *(const bf16x8*)(xs + rowc * 136 + kk * 32 + kq * 8);
    }
#pragma unroll
    for (int ct = 0; ct < 2; ++ct)
#pragma unroll
      for (int rt = 0; rt < 4; ++rt)
        acc[ct][rt] = __builtin_amdgcn_mfma_f32_16x16x32_bf16(wf[ct][kk], xf[rt], acc[ct][rt], 0, 0, 0);
  }
  // lane holds out[row = rt*16+r16][col0..col0+3], col0 = n0+ct*16+kq*4
#pragma unroll
  for (int ct = 0; ct < 2; ++ct) {
    const int col0 = n0 + ct * 16 + kq * 4;
    const float4 b4 = *(const float4*)(bias + col0);
#pragma unroll
    for (int rt = 0; rt < 4; ++rt) {
      const int row = rt * 16 + r16;
      if (row < 52) {
        ushort4 o;
        o.x = bfbits(acc[ct][rt][0] + b4.x);
        o.y = bfbits(acc[ct][rt][1] + b4.y);
        o.z = bfbits(acc[ct][rt][2] + b4.z);
        o.w = bfbits(acc[ct][rt][3] + b4.w);
        *(ushort4*)(out + row * 136 + col0) = o;
      }
    }
  }
}

__device__ __forceinline__ uint2 shfl64(uint2 v, int lane) {
  uint2 r;
  r.x = (unsigned)__shfl((int)v.x, lane);
  r.y = (unsigned)__shfl((int)v.y, lane);
  return r;
}

__global__ __launch_bounds__(256, 3) void attn_fused_kernel(
    const float* __restrict__ Qin, const float* __restrict__ Kin,
    const float* __restrict__ Vin,
    const __hip_bfloat16* __restrict__ WqT, const float* __restrict__ bq,
    const __hip_bfloat16* __restrict__ WkT, const float* __restrict__ bk,
    const __hip_bfloat16* __restrict__ WvT, const float* __restrict__ bv,
    __hip_bfloat16* __restrict__ Oc,
    const float* __restrict__ Wo, __hip_bfloat16* __restrict__ WoT) {
  __shared__ __align__(16) char lds[42432];
  const int gid = blockIdx.x;
  const int t = threadIdx.x;

  if (gid >= 2048) {
    // ---------------- Wo transpose tile (64x64) ----------------
    float* tile = (float*)lds;                     // [64][65] = 16640 B
    const int bid2 = gid - 2048;
    const int nt = bid2 & 63, mt = bid2 >> 6;
    const int r  = t >> 4;
    const int c4 = (t & 15) << 2;
#pragma unroll
    for (int p = 0; p < 4; ++p) {
      const int rr = r + p * 16;
      const float4 v = *(const float4*)(Wo + (size_t)(mt * 64 + rr) * 4096 + nt * 64 + c4);
      tile[rr * 65 + c4 + 0] = v.x; tile[rr * 65 + c4 + 1] = v.y;
      tile[rr * 65 + c4 + 2] = v.z; tile[rr * 65 + c4 + 3] = v.w;
    }
    __syncthreads();
#pragma unroll
    for (int p = 0; p < 4; ++p) {
      const int rr = r + p * 16;
      union { __hip_bfloat16 h[4]; ushort4 u; } o4;
#pragma unroll
      for (int e = 0; e < 4; ++e) o4.h[e] = __float2bfloat16(tile[(c4 + e) * 65 + rr]);
      *(ushort4*)(WoT + (size_t)(nt * 64 + rr) * 4096 + mt * 64 + c4) = o4.u;
    }
    return;
  }

  // ---------------- attention block ----------------
  __hip_bfloat16* r0 = (__hip_bfloat16*)(lds);           // xs_q -> k_sh -> p_sh
  __hip_bfloat16* r1 = (__hip_bfloat16*)(lds + 14144);   // xs_k -> s_sh
  __hip_bfloat16* r2 = (__hip_bfloat16*)(lds + 28288);   // xs_v -> q_sh
  float*          s_sh = (float*)(lds + 14144);          // 52 x 68 f32
  __hip_bfloat16* p_sh = r0;                             // 52 x 72 bf16

  const int h = gid & 31, bb = gid >> 5;
  const int lane = t & 63;
  const int w = t >> 6;
  const int r16 = lane & 15, kq = lane >> 4;
  const size_t xoff = (size_t)bb * (L_SZ * DMODEL) + (size_t)h * (L_SZ * C_SZ);
  const int n0 = w * 32;

  // ---- P0: batched staging, software-pipelined (MLP ~14 outstanding) ----
#define LOADR(G, XP)                                                           \
  _Pragma("unroll")                                                            \
  for (int j = 0; j < 7; ++j) {                                                \
    const int idx = t + j * 256;                                               \
    if (idx < 1664)                                                            \
      G[j] = *(const float4*)((XP) + (idx >> 5) * 128 + ((idx & 31) << 2));    \
  }
#define STORER(G, XD)                                                          \
  _Pragma("unroll")                                                            \
  for (int j = 0; j < 7; ++j) {                                                \
    const int idx = t + j * 256;                                               \
    if (idx < 1664) {                                                          \
      ushort4 o;                                                               \
      o.x = bfbits(G[j].x); o.y = bfbits(G[j].y);                              \
      o.z = bfbits(G[j].z); o.w = bfbits(G[j].w);                              \
      *(ushort4*)((XD) + (idx >> 5) * 136 + ((idx & 31) << 2)) = o;            \
    }                                                                          \
  }
  bf16x8 wfv[2][4];
  {
    float4 ga[7], gb[7];
    LOADR(ga, Qin + xoff)
    LOADR(gb, Kin + xoff)
    // Wv fragment preload overlaps the X loads (used first after B1)
    const __hip_bfloat16* WTv = WvT + (size_t)h * 16384;
#pragma unroll
    for (int ct = 0; ct < 2; ++ct)
#pragma unroll
      for (int kk = 0; kk < 4; ++kk)
        wfv[ct][kk] = *(const bf16x8*)(WTv + (n0 + ct * 16 + r16) * 128 + kk * 32 + kq * 8);
    STORER(ga, r0)
    LOADR(ga, Vin + xoff)
    STORER(gb, r1)
    STORER(ga, r2)
  }
  __syncthreads();   // B1

  // ---- P1: vproj -> registers (unswapped; vb[mt][ct] rows kq*4..+3) ----
  uint2 vb[4][2];
  {
    f32x4 acc[4][2] = {};
#pragma unroll
    for (int kk = 0; kk < 4; ++kk) {
      bf16x8 a[4];
#pragma unroll
      for (int mt = 0; mt < 4; ++mt) {
        const int row = mt * 16 + r16;
        const int rowc = row < 52 ? row : 51;
        a[mt] = *(const bf16x8*)(r2 + rowc * 136 + kk * 32 + kq * 8);
      }
#pragma unroll
      for (int mt = 0; mt < 4; ++mt)
#pragma unroll
        for (int ct = 0; ct < 2; ++ct)
          acc[mt][ct] = __builtin_amdgcn_mfma_f32_16x16x32_bf16(a[mt], wfv[ct][kk], acc[mt][ct], 0, 0, 0);
    }
#pragma unroll
    for (int ct = 0; ct < 2; ++ct) {
      const float bvv = bv[h * 128 + n0 + ct * 16 + r16];
#pragma unroll
      for (int mt = 0; mt < 4; ++mt) {
        vb[mt][ct].x = (unsigned)bfbits(acc[mt][ct][0] + bvv) |
                       ((unsigned)bfbits(acc[mt][ct][1] + bvv) << 16);
        vb[mt][ct].y = (unsigned)bfbits(acc[mt][ct][2] + bvv) |
                       ((unsigned)bfbits(acc[mt][ct][3] + bvv) << 16);
      }
    }
  }
  __syncthreads();   // B2 (vproj done reading r2)

  // ---- P2: qproj r0 -> r2 (swapped, b64 stores) ----
  proj_swap136(r0, WqT + (size_t)h * 16384, bq + h * 128, r2, n0, r16, kq);
  __syncthreads();   // B3

  // ---- P3: kproj r1 -> r0 (swapped) ----
  proj_swap136(r1, WkT + (size_t)h * 16384, bk + h * 128, r0, n0, r16, kq);
  __syncthreads();   // B4

  // ---- P4: QK^T: q(r2) x k(r0) -> s_sh(r1), scaled ----
  {
    const int nq = w * 16;
    f32x4 sacc[4] = {};
#pragma unroll
    for (int kk = 0; kk < 4; ++kk) {
      const int krow = nq + r16;
      const int krc = krow < 52 ? krow : 51;
      const bf16x8 kf = *(const bf16x8*)(r0 + krc * 136 + kk * 32 + kq * 8);
#pragma unroll
      for (int mt = 0; mt < 4; ++mt) {
        const int qrow = mt * 16 + r16;
        const int qrc = qrow < 52 ? qrow : 51;
        const bf16x8 a = *(const bf16x8*)(r2 + qrc * 136 + kk * 32 + kq * 8);
        sacc[mt] = __builtin_amdgcn_mfma_f32_16x16x32_bf16(a, kf, sacc[mt], 0, 0, 0);
      }
    }
    const float scale = 0.08838834764831845f;  // 1/sqrt(128)
#pragma unroll
    for (int mt = 0; mt < 4; ++mt)
#pragma unroll
      for (int i = 0; i < 4; ++i) {
        const int row = mt * 16 + kq * 4 + i;
        if (row < 52) s_sh[row * 68 + nq + r16] = sacc[mt][i] * scale;
      }
  }
  __syncthreads();   // B5

  // ---- P5: masked softmax s_sh(r1) -> p_sh(r0, stride 72) ----
  {
    const int r = t >> 2, qd = t & 3;   // 4 lanes/row, 16 cols each
    if (r < 52) {
      float v[16];
      float mx = -3e38f;
#pragma unroll
      for (int j4 = 0; j4 < 4; ++j4) {
        const f32x4 s4 = *(const f32x4*)(s_sh + r * 68 + qd * 16 + j4 * 4);
#pragma unroll
        for (int e = 0; e < 4; ++e) {
          const int col = qd * 16 + j4 * 4 + e;
          const float val = (col <= r) ? s4[e] : -3e38f;
          v[j4 * 4 + e] = val;
          mx = fmaxf(mx, val);
        }
      }
      mx = fmaxf(mx, __shfl_xor(mx, 1));
      mx = fmaxf(mx, __shfl_xor(mx, 2));
      float ex[16];
      float sum = 0.f;
#pragma unroll
      for (int j = 0; j < 16; ++j) {
        const int col = qd * 16 + j;
        const float e = (col <= r) ? __expf(v[j] - mx) : 0.f;
        ex[j] = e; sum += e;
      }
      sum += __shfl_xor(sum, 1);
      sum += __shfl_xor(sum, 2);
      const float inv = 1.0f / sum;
      union { __hip_bfloat16 h[8]; uint4 q; } p0, p1;
#pragma unroll
      for (int j = 0; j < 8; ++j) {
        p0.h[j] = __float2bfloat16(ex[j] * inv);
        p1.h[j] = __float2bfloat16(ex[8 + j] * inv);
      }
      *(uint4*)(p_sh + r * 72 + qd * 16)     = p0.q;
      *(uint4*)(p_sh + r * 72 + qd * 16 + 8) = p1.q;
    }
  }
  __syncthreads();   // B6

  // ---- P6: PV (swapped): mfma(v_frag, p_frag); ushort4 Oc stores ----
  {
    const int half = (kq >> 1) & 1;
    const int src0 = ((kq & 1) << 5) + r16;
    const int src1 = src0 + 16;
    f32x4 oaccT[2][4] = {};   // [v-col block ct][q-row block rt]
#pragma unroll
    for (int kk = 0; kk < 2; ++kk) {
      bf16x8 bfr[2];
#pragma unroll
      for (int ct = 0; ct < 2; ++ct) {
        const uint2 a0 = shfl64(vb[2 * kk + 0][ct], src0);
        const uint2 a1 = shfl64(vb[2 * kk + 1][ct], src0);
        const uint2 b0 = shfl64(vb[2 * kk + 0][ct], src1);
        const uint2 b1 = shfl64(vb[2 * kk + 1][ct], src1);
        union { unsigned u[4]; bf16x8 v; } asm_;
        asm_.u[0] = half ? a1.x : a0.x;
        asm_.u[1] = half ? a1.y : a0.y;
        asm_.u[2] = half ? b1.x : b0.x;
        asm_.u[3] = half ? b1.y : b0.y;
        bfr[ct] = asm_.v;
      }
      bf16x8 pf[4];
#pragma unroll
      for (int rt = 0; rt < 4; ++rt) {
        const int prow = rt * 16 + r16;
        const int prc = prow < 52 ? prow : 51;
        pf[rt] = *(const bf16x8*)(p_sh + prc * 72 + kk * 32 + kq * 8);
      }
#pragma unroll
      for (int ct = 0; ct < 2; ++ct)
#pragma unroll
        for (int rt = 0; rt < 4; ++rt)
          oaccT[ct][rt] = __builtin_amdgcn_mfma_f32_16x16x32_bf16(bfr[ct], pf[rt], oaccT[ct][rt], 0, 0, 0);
    }
    const size_t obase = (size_t)bb * 52 * 4096 + (size_t)h * 128;
#pragma unroll
    for (int ct = 0; ct < 2; ++ct) {
      const int col0 = n0 + ct * 16 + kq * 4;
#pragma unroll
      for (int rt = 0; rt < 4; ++rt) {
        const int row = rt * 16 + r16;
        if (row < 52) {
          ushort4 o;
          o.x = bfbits(oaccT[ct][rt][0]);
          o.y = bfbits(oaccT[ct][rt][1]);
          o.z = bfbits(oaccT[ct][rt][2]);
          o.w = bfbits(oaccT[ct][rt][3]);
          *(ushort4*)(Oc + obase + (size_t)row * 4096 + col0) = o;
        }
      }
    }
  }
}

// ---------------------------------------------------------------------------
// Kernel 3: C = Oc @ WoT^T + bo — 4-phase/K-tile schedule, x2-unrolled,
// swapped operands + float4 epilogue (as R11). CHANGE vs R11: removed the
// forced `s_waitcnt lgkmcnt(0)` + sched_barrier(0) before each MFMA cluster —
// the ds_read->MFMA register dependency lets the compiler emit fine-grained
// counted lgkmcnt waits, so early MFMAs start while later reads drain
// (removes the ~220-cyc full-drain serialization per phase).
// Safety: every ds_read is consumed by an MFMA before the phase-end barrier
// (counted wait => data in regs); staging only overwrites regions whose
// readers' MFMAs completed before an intervening s_barrier.
// ---------------------------------------------------------------------------
#define STAGE(GBASE, REGOFF, KT, KS, WB) do {                                  \
    const __hip_bfloat16* s_ = (GBASE) + (size_t)(KT) * 64 + (KS) * 32;        \
    char* d_ = (WB) + (REGOFF) + ((KS) ? 16384 : 0) + t * 16;                  \
    gload_lds16(s_, d_);                                                       \
    gload_lds16(s_ + (size_t)128 * GK, d_ + 8192);                             \
  } while (0)

#define MFMA16(MQ, BF)                                                         \
  __builtin_amdgcn_s_setprio(1);                                               \
  _Pragma("unroll")                                                            \
  for (int mf = 0; mf < 4; ++mf)                                               \
    _Pragma("unroll")                                                          \
    for (int nf = 0; nf < 4; ++nf)                                             \
      acc[(MQ) * 4 + mf][nf] = __builtin_amdgcn_mfma_f32_16x16x32_bf16(        \
          BF[nf], af[mf], acc[(MQ) * 4 + mf][nf], 0, 0, 0);                    \
  __builtin_amdgcn_s_setprio(0)

#define READ_AF(RB, KS, MQ)                                                    \
  _Pragma("unroll")                                                            \
  for (int mf = 0; mf < 4; ++mf)                                               \
    af[mf] = *(const bf16x8*)((RB) + (KS) * 16384 + (MQ) * 4096 + aB0 + mf * 1024)

#define READ_BF(RB, BF, KS)                                                    \
  _Pragma("unroll")                                                            \
  for (int nf = 0; nf < 4; ++nf)                                               \
    BF[nf] = *(const bf16x8*)((RB) + 32768 + (KS) * 16384 + bB0 + nf * 1024)

#define KTILE_BODY(KT, RB, OB) do {                                            \
    const int s1 = (KT) + 1 < 64 ? (KT) + 1 : 63;                              \
    const int s2 = (KT) + 2 < 64 ? (KT) + 2 : 63;                              \
    {                                                                          \
      bf16x8 af[4];                                                            \
      READ_AF(RB, 0, 0);                                                       \
      READ_BF(RB, bf0, 0);                                                     \
      STAGE(gA0, 0, s1, 1, OB);                                                \
      __builtin_amdgcn_s_barrier();                                            \
      MFMA16(0, bf0);                                                          \
      __builtin_amdgcn_s_barrier();                                            \
    }                                                                          \
    {                                                                          \
      bf16x8 af[4];                                                            \
      READ_AF(RB, 0, 1);                                                       \
      STAGE(gB0, 32768, s2, 0, RB);                                            \
      __builtin_amdgcn_s_barrier();                                            \
      MFMA16(1, bf0);                                                          \
      __builtin_amdgcn_s_barrier();                                            \
    }                                                                          \
    {                                                                          \
      bf16x8 af[4];                                                            \
      READ_AF(RB, 1, 0);                                                       \
      READ_BF(RB, bf1, 1);                                                     \
      STAGE(gA0, 0, s2, 0, RB);                                                \
      __builtin_amdgcn_s_barrier();                                            \
      MFMA16(0, bf1);                                                          \
      __builtin_amdgcn_s_barrier();                                            \
    }                                                                          \
    {                                                                          \
      bf16x8 af[4];                                                            \
      READ_AF(RB, 1, 1);                                                       \
      STAGE(gB0, 32768, s2, 1, RB);                                            \
      __builtin_amdgcn_s_barrier();                                            \
      MFMA16(1, bf1);                                                          \
      asm volatile("s_waitcnt vmcnt(6)" ::: "memory");                         \
      __builtin_amdgcn_s_barrier();                                            \
    }                                                                          \
  } while (0)

__global__ __launch_bounds__(512, 2) void out_gemm_kernel(
    const __hip_bfloat16* __restrict__ A, const __hip_bfloat16* __restrict__ Bt,
    const float* __restrict__ bias, float* __restrict__ C) {
  __shared__ __align__(16) char lds[131072];   // 2 bufs x 64 KB

  int bid = blockIdx.x;
  bid = (bid & 7) * 26 + (bid >> 3);     // XCD swizzle, 208 % 8 == 0 (bijective)
  const int tm = bid >> 4;               // 0..12
  const int tn = bid & 15;               // 0..15

  const int t = threadIdx.x;
  const int w = t >> 6, lane = t & 63;
  const int wm = w >> 2, wn = w & 3;     // 2M x 4N waves; wave tile 128x64
  const int r16 = lane & 15, kq = lane >> 4;

  const int srow = t >> 2;
  const int sgslot = (t & 3) ^ ((srow >> 1) & 3);
  const __hip_bfloat16* gA0 = A  + (size_t)(tm * 256 + srow) * GK + sgslot * 8;
  const __hip_bfloat16* gB0 = Bt + (size_t)(tn * 256 + srow) * GK + sgslot * 8;

  const int slotr = kq ^ ((r16 >> 1) & 3);
  const int aB0 = (wm * 128 + r16) * 64 + slotr * 16;
  const int bB0 = (wn * 64 + r16) * 64 + slotr * 16;

  f32x4 acc[8][4] = {};
  bf16x8 bf0[4], bf1[4];

  char* const buf0 = lds;
  char* const buf1 = lds + 65536;

  STAGE(gA0, 0,     0, 0, buf0);
  STAGE(gA0, 0,     0, 1, buf0);
  STAGE(gB0, 32768, 0, 0, buf0);
  STAGE(gB0, 32768, 0, 1, buf0);
  STAGE(gB0, 32768, 1, 0, buf1);
  STAGE(gA0, 0,     1, 0, buf1);
  STAGE(gB0, 32768, 1, 1, buf1);
  asm volatile("s_waitcnt vmcnt(6)" ::: "memory");   // T0's 8 loads landed
  __builtin_amdgcn_s_barrier();

#pragma unroll 1
  for (int kt2 = 0; kt2 < 32; ++kt2) {
    const int kt = kt2 * 2;
    KTILE_BODY(kt,     buf0, buf1);
    KTILE_BODY(kt + 1, buf1, buf0);
  }
  asm volatile("s_waitcnt vmcnt(0) lgkmcnt(0)" ::: "memory");

  // epilogue (swapped): lane holds C[row0+mf*16][col0 + nf*16 .. +3]
  const int row0 = tm * 256 + wm * 128 + r16;
  const int col0 = tn * 256 + wn * 64 + kq * 4;
  float4 b4[4];
#pragma unroll
  for (int nf = 0; nf < 4; ++nf)
    b4[nf] = *(const float4*)(bias + col0 + nf * 16);
#pragma unroll
  for (int mf = 0; mf < 8; ++mf) {
    const int row = row0 + mf * 16;
#pragma unroll
    for (int nf = 0; nf < 4; ++nf) {
      float4 st;
      st.x = acc[mf][nf][0] + b4[nf].x;
      st.y = acc[mf][nf][1] + b4[nf].y;
      st.z = acc[mf][nf][2] + b4[nf].z;
      st.w = acc[mf][nf][3] + b4[nf].w;
      *(float4*)(C + (size_t)row * GN + col0 + nf * 16) = st;
    }
  }
}

// ---------------------------------------------------------------------------
extern "C" void kernel_launch(void* const* d_in, const int* in_sizes, int n_in,
                              void* d_out, int out_size, void* d_ws, size_t ws_size,
                              hipStream_t stream) {
  const float* Q  = (const float*)d_in[0];
  const float* K  = (const float*)d_in[1];
  const float* V  = (const float*)d_in[2];
  const float* Wq = (const float*)d_in[3];
  const float* bq = (const float*)d_in[4];
  const float* Wk = (const float*)d_in[5];
  const float* bk = (const float*)d_in[6];
  const float* Wv = (const float*)d_in[7];
  const float* bv = (const float*)d_in[8];
  const float* Wo = (const float*)d_in[9];
  const float* bo = (const float*)d_in[10];
  float* out = (float*)d_out;

  char* wsb = (char*)d_ws;
  __hip_bfloat16* WoT = (__hip_bfloat16*)wsb;
  __hip_bfloat16* Oc  = (__hip_bfloat16*)(wsb + (size_t)GN * GK * 2);
  __hip_bfloat16* WqT = (__hip_bfloat16*)(wsb + (size_t)GN * GK * 2 + (size_t)GM * GN * 2);
  __hip_bfloat16* WkT = WqT + (size_t)H_SZ * C_SZ * DK;
  __hip_bfloat16* WvT = WkT + (size_t)H_SZ * C_SZ * DK;

  w3_transpose_kernel<<<dim3(2, 2, 96), 256, 0, stream>>>(Wq, Wk, Wv, WqT, WkT, WvT);
  attn_fused_kernel<<<dim3(2048 + 4096), 256, 0, stream>>>(
      Q, K, V, WqT, bq, WkT, bk, WvT, bv, Oc, Wo, WoT);
  out_gemm_kernel<<<dim3(13 * 16), 512, 0, stream>>>(Oc, WoT, bo, out);
}